// Round 1
// baseline (27371.002 us; speedup 1.0000x reference)
//
#include <hip/hip_runtime.h>
#include <hip/hip_cooperative_groups.h>

namespace cg = cooperative_groups;

// Problem dims
#define BATCH   256
#define T_STEPS 512
#define IN_DIM  256
#define HID     1024
#define KTOT    1280   // IN_DIM + HID

typedef __attribute__((ext_vector_type(4))) float f32x4;
typedef __attribute__((ext_vector_type(8))) short bf16x8;

__device__ inline short f2bf(float f) {
    union { float f; unsigned u; } v; v.f = f;
    unsigned u = v.u;
    unsigned r = (u + 0x7fffu + ((u >> 16) & 1u)) >> 16;  // RNE
    return (short)r;
}

__device__ inline float sigmoidf_fast(float x) {
    return __builtin_amdgcn_rcpf(1.0f + __expf(-x));
}
__device__ inline float tanhf_fast(float x) {
    // tanh(x) = 1 - 2/(exp(2x)+1); saturates correctly at +/-inf
    return 1.0f - 2.0f * __builtin_amdgcn_rcpf(1.0f + __expf(2.0f * x));
}

// Build w_cat bf16 [4096][1280] = [w_ih | w_hh] rows (N-major, K contiguous)
__global__ void prep_wcat(const float* __restrict__ wih, const float* __restrict__ whh,
                          short* __restrict__ wcat) {
    int i = blockIdx.x * 256 + threadIdx.x;
    if (i >= 4096 * KTOT) return;
    int g = i / KTOT;
    int k = i - g * KTOT;
    float v = (k < IN_DIM) ? wih[g * IN_DIM + k] : whh[(size_t)g * HID + (k - IN_DIM)];
    wcat[i] = f2bf(v);
}

// bias_comb = b_ih + b_hh; zero h buffers; zero output
__global__ void prep_misc(const float* __restrict__ bih, const float* __restrict__ bhh,
                          float* __restrict__ bias, short* __restrict__ h0,
                          short* __restrict__ h1, float* __restrict__ out) {
    int i = blockIdx.x * 256 + threadIdx.x;   // grid covers 262144
    if (i < 4096) bias[i] = bih[i] + bhh[i];
    if (i < BATCH * HID) { h0[i] = 0; h1[i] = 0; }
    if (i < BATCH) out[i] = 0.0f;
}

// Persistent cooperative LSTM kernel.
// Grid: 256 blocks (4 M-tiles x 64 j-tiles), 256 threads (4 waves).
// Block covers batch rows [m0, m0+64) x hidden cols [j0, j0+16) for all 4 gates.
// Wave wv computes M-subtile [m0+16*wv, +16) x 16 cols x 4 gates (4 MFMA accs).
__global__ __launch_bounds__(256, 1) void lstm_main(
    const float* __restrict__ x, const short* __restrict__ wcat,
    const float* __restrict__ bias, const float* __restrict__ fcw,
    const float* __restrict__ fcb, short* __restrict__ h0,
    short* __restrict__ h1, float* __restrict__ out)
{
    const int tid  = threadIdx.x;
    const int lane = tid & 63;
    const int wv   = tid >> 6;          // 0..3 -> M-subtile
    const int blk  = blockIdx.x;
    const int m0   = (blk >> 6) * 64;   // batch tile base
    const int j0   = (blk & 63) * 16;   // hidden-col tile base
    const int r16  = lane & 15;
    const int kq   = lane >> 4;         // 0..3

    // A-operand row this lane loads (A[m=lane&15][k=kq*8+j])
    const int mrow = m0 + wv * 16 + r16;
    // C/D + B column this lane covers
    const int jc   = j0 + r16;

    // B pointers: one row of w_cat per gate (B[k][n] == w_cat[n][k])
    const short* wp0 = wcat + (size_t)(0 * HID + jc) * KTOT + kq * 8;
    const short* wp1 = wcat + (size_t)(1 * HID + jc) * KTOT + kq * 8;
    const short* wp2 = wcat + (size_t)(2 * HID + jc) * KTOT + kq * 8;
    const short* wp3 = wcat + (size_t)(3 * HID + jc) * KTOT + kq * 8;

    // biases depend only on column -> hoist for all 512 steps
    const float bi = bias[jc];
    const float bf = bias[HID + jc];
    const float bg = bias[2 * HID + jc];
    const float bo = bias[3 * HID + jc];

    const float* xrow = x + (size_t)mrow * T_STEPS * IN_DIM + kq * 8;

    float c[4] = {0.f, 0.f, 0.f, 0.f};   // cell state, register-resident all steps

    cg::grid_group grid = cg::this_grid();

    for (int t = 0; t < T_STEPS; ++t) {
        const short* hcur  = (t & 1) ? h1 : h0;
        short*       hnext = (t & 1) ? h0 : h1;

        f32x4 aI = {0.f, 0.f, 0.f, 0.f};
        f32x4 aF = {0.f, 0.f, 0.f, 0.f};
        f32x4 aG = {0.f, 0.f, 0.f, 0.f};
        f32x4 aO = {0.f, 0.f, 0.f, 0.f};

        // --- x phase: K = 0..255 (fp32 -> bf16 on the fly) ---
        const float* xp = xrow + (size_t)t * IN_DIM;
        #pragma unroll
        for (int kk = 0; kk < IN_DIM; kk += 32) {
            f32x4 f0 = *(const f32x4*)(xp + kk);
            f32x4 f1 = *(const f32x4*)(xp + kk + 4);
            bf16x8 a;
            a[0] = f2bf(f0[0]); a[1] = f2bf(f0[1]); a[2] = f2bf(f0[2]); a[3] = f2bf(f0[3]);
            a[4] = f2bf(f1[0]); a[5] = f2bf(f1[1]); a[6] = f2bf(f1[2]); a[7] = f2bf(f1[3]);
            aI = __builtin_amdgcn_mfma_f32_16x16x32_bf16(a, *(const bf16x8*)(wp0 + kk), aI, 0, 0, 0);
            aF = __builtin_amdgcn_mfma_f32_16x16x32_bf16(a, *(const bf16x8*)(wp1 + kk), aF, 0, 0, 0);
            aG = __builtin_amdgcn_mfma_f32_16x16x32_bf16(a, *(const bf16x8*)(wp2 + kk), aG, 0, 0, 0);
            aO = __builtin_amdgcn_mfma_f32_16x16x32_bf16(a, *(const bf16x8*)(wp3 + kk), aO, 0, 0, 0);
        }

        // --- h phase: K = 256..1279 (bf16 recurrent input) ---
        const short* hp = hcur + (size_t)mrow * HID + kq * 8;
        #pragma unroll 4
        for (int kk = 0; kk < HID; kk += 32) {
            bf16x8 a = *(const bf16x8*)(hp + kk);
            aI = __builtin_amdgcn_mfma_f32_16x16x32_bf16(a, *(const bf16x8*)(wp0 + IN_DIM + kk), aI, 0, 0, 0);
            aF = __builtin_amdgcn_mfma_f32_16x16x32_bf16(a, *(const bf16x8*)(wp1 + IN_DIM + kk), aF, 0, 0, 0);
            aG = __builtin_amdgcn_mfma_f32_16x16x32_bf16(a, *(const bf16x8*)(wp2 + IN_DIM + kk), aG, 0, 0, 0);
            aO = __builtin_amdgcn_mfma_f32_16x16x32_bf16(a, *(const bf16x8*)(wp3 + IN_DIM + kk), aO, 0, 0, 0);
        }

        // --- cell update, fully in registers ---
        // acc[r] = gates[m0 + wv*16 + kq*4 + r][jc]
        const int mbase = m0 + wv * 16 + kq * 4;
        #pragma unroll
        for (int r = 0; r < 4; ++r) {
            float iv = aI[r] + bi;
            float fv = aF[r] + bf;
            float gv = aG[r] + bg;
            float ov = aO[r] + bo;
            float ig = sigmoidf_fast(iv);
            float fg = sigmoidf_fast(fv);
            float gg = tanhf_fast(gv);
            float og = sigmoidf_fast(ov);
            c[r] = fg * c[r] + ig * gg;
            float h = og * tanhf_fast(c[r]);
            hnext[(size_t)(mbase + r) * HID + jc] = f2bf(h);
        }

        grid.sync();
    }

    // --- epilogue: out[b] = sum_j c[b,j]*fcw[j] + fcb ---
    const float fw = fcw[jc];
    #pragma unroll
    for (int r = 0; r < 4; ++r) {
        float v = c[r] * fw;
        // reduce across the 16 lanes (r16) sharing the same output row
        v += __shfl_xor(v, 1, 64);
        v += __shfl_xor(v, 2, 64);
        v += __shfl_xor(v, 4, 64);
        v += __shfl_xor(v, 8, 64);
        if (r16 == 0) {
            int mm = m0 + wv * 16 + kq * 4 + r;
            float add = v;
            if (j0 == 0) add += fcb[0];   // bias added exactly once per row
            atomicAdd(&out[mm], add);
        }
    }
}

extern "C" void kernel_launch(void* const* d_in, const int* in_sizes, int n_in,
                              void* d_out, int out_size, void* d_ws, size_t ws_size,
                              hipStream_t stream)
{
    const float* x   = (const float*)d_in[0];
    const float* wih = (const float*)d_in[1];
    const float* whh = (const float*)d_in[2];
    const float* bih = (const float*)d_in[3];
    const float* bhh = (const float*)d_in[4];
    const float* fcw = (const float*)d_in[5];
    const float* fcb = (const float*)d_in[6];
    float* out = (float*)d_out;

    char* ws = (char*)d_ws;
    short* wcat = (short*)ws;                                   // 4096*1280*2 = 10,485,760 B
    float* bias = (float*)(ws + 10485760);                      // 16,384 B
    short* h0   = (short*)(ws + 10485760 + 16384);              // 524,288 B
    short* h1   = h0 + BATCH * HID;                             // 524,288 B  (total ~11.5 MB)

    prep_wcat<<<(4096 * KTOT + 255) / 256, 256, 0, stream>>>(wih, whh, wcat);
    prep_misc<<<(BATCH * HID + 255) / 256, 256, 0, stream>>>(bih, bhh, bias, h0, h1, out);

    void* args[] = { (void*)&x, (void*)&wcat, (void*)&bias, (void*)&fcw, (void*)&fcb,
                     (void*)&h0, (void*)&h1, (void*)&out };
    hipLaunchCooperativeKernel((void*)lstm_main, dim3(256), dim3(256), args, 0, stream);
}

// Round 2
// 19384.723 us; speedup vs baseline: 1.4120x; 1.4120x over previous
//
#include <hip/hip_runtime.h>
#include <hip/hip_cooperative_groups.h>

namespace cg = cooperative_groups;

// Problem dims
#define BATCH   256
#define T_STEPS 512
#define IN_DIM  256
#define HID     1024
#define KTOT    1280   // IN_DIM + HID
#define NCK     40     // K chunks of 32
#define CKW     10     // chunks per wave (K-quarter)

typedef __attribute__((ext_vector_type(4))) float f32x4;
typedef __attribute__((ext_vector_type(2))) float f32x2;
typedef __attribute__((ext_vector_type(8))) short bf16x8;

__device__ inline short f2bf(float f) {
    union { float f; unsigned u; } v; v.f = f;
    unsigned u = v.u;
    unsigned r = (u + 0x7fffu + ((u >> 16) & 1u)) >> 16;  // RNE
    return (short)r;
}

__device__ inline float sigmoidf_fast(float x) {
    return __builtin_amdgcn_rcpf(1.0f + __expf(-x));
}
__device__ inline float tanhf_fast(float x) {
    return 1.0f - 2.0f * __builtin_amdgcn_rcpf(1.0f + __expf(2.0f * x));
}

// Build w_cat bf16 [4096][1280] = [w_ih | w_hh] rows (N-major, K contiguous)
__global__ void prep_wcat(const float* __restrict__ wih, const float* __restrict__ whh,
                          short* __restrict__ wcat) {
    int i = blockIdx.x * 256 + threadIdx.x;
    if (i >= 4096 * KTOT) return;
    int g = i / KTOT;
    int k = i - g * KTOT;
    float v = (k < IN_DIM) ? wih[g * IN_DIM + k] : whh[(size_t)g * HID + (k - IN_DIM)];
    wcat[i] = f2bf(v);
}

// bias_comb = b_ih + b_hh; zero h buffers; zero output
__global__ void prep_misc(const float* __restrict__ bih, const float* __restrict__ bhh,
                          float* __restrict__ bias, short* __restrict__ h0,
                          short* __restrict__ h1, float* __restrict__ out) {
    int i = blockIdx.x * 256 + threadIdx.x;
    if (i < 4096) bias[i] = bih[i] + bhh[i];
    if (i < BATCH * HID) { h0[i] = 0; h1[i] = 0; }
    if (i < BATCH) out[i] = 0.0f;
}

// Persistent cooperative LSTM kernel, register-resident weights.
// Grid: 256 blocks = 4 m-tiles (64 rows) x 64 j-tiles (16 cols, all 4 gates).
// Block: 512 threads = 8 waves = (m-half mh in {0,1}) x (K-quarter kw in {0..3}).
// Each wave holds its B-fragments (10 chunks x 4 gates = 160 VGPRs) in registers
// for ALL 512 steps. Per step: 8 MFMAs per chunk (2 m-subtiles x 4 gates),
// 4-way K-partial reduction through 64 KB LDS, fused cell update, h -> global.
__global__ __launch_bounds__(512, 2) void lstm_main(
    const float* __restrict__ x, const short* __restrict__ wcat,
    const float* __restrict__ bias, const float* __restrict__ fcw,
    const float* __restrict__ fcb, short* __restrict__ h0,
    short* __restrict__ h1, float* __restrict__ out)
{
    extern __shared__ float q[];   // [kw][g][mgrp][lane][4] = 4*4*4*64*4 floats = 64 KB

    const int tid = threadIdx.x;
    const int l   = tid & 63;
    const int u   = tid >> 6;        // wave 0..7
    const int mh  = u >> 2;          // m-half 0..1
    const int kw  = u & 3;           // K-quarter 0..3
    const int lq  = l >> 4;          // lane quad 0..3
    const int r16 = l & 15;
    const int m0  = (blockIdx.x >> 6) * 64;
    const int j0  = (blockIdx.x & 63) * 16;
    const int jc  = j0 + r16;

    // ---- persistent B fragments: 10 chunks x 4 gates, 160 VGPRs ----
    bf16x8 Bf[CKW][4];
    #pragma unroll
    for (int i = 0; i < CKW; ++i) {
        const int k = (kw * CKW + i) * 32 + lq * 8;
        #pragma unroll
        for (int g = 0; g < 4; ++g)
            Bf[i][g] = *(const bf16x8*)(wcat + (size_t)(g * HID + jc) * KTOT + k);
    }

    // ---- update-phase cell ownership: 2 cells per thread ----
    const int mgrp  = u >> 1;            // 0..3 (m>>4 group)
    const int rp    = (u & 1) * 2;       // r-pair base
    const int mcell = mgrp * 16 + lq * 4 + rp;   // block-local rows mcell, mcell+1, col jc
    float bia[4];
    #pragma unroll
    for (int g = 0; g < 4; ++g) bia[g] = bias[g * HID + jc];
    float c0 = 0.f, c1 = 0.f;            // cell state, register-resident all 512 steps

    // ---- A-operand addressing (rows m0 + mh*32 + {0,16} + r16) ----
    const int mA0 = m0 + mh * 32 + r16;
    const float* xb0 = x + (size_t)mA0 * (T_STEPS * IN_DIM) + lq * 8;
    const float* xb1 = x + (size_t)(mA0 + 16) * (T_STEPS * IN_DIM) + lq * 8;

    cg::grid_group grid = cg::this_grid();

    for (int t = 0; t < T_STEPS; ++t) {
        const short* hcur  = (t & 1) ? h1 : h0;
        short*       hnext = (t & 1) ? h0 : h1;

        f32x4 acc[2][4] = {};   // [m-subtile][gate]

        #pragma unroll
        for (int i = 0; i < CKW; ++i) {
            const int ci = kw * CKW + i;
            bf16x8 a0, a1;
            if (ci < 8) {
                // x chunk: fp32 load + convert (only kw==0 waves take this path)
                const float* p0 = xb0 + (size_t)t * IN_DIM + ci * 32;
                const float* p1 = xb1 + (size_t)t * IN_DIM + ci * 32;
                f32x4 u00 = ((const f32x4*)p0)[0], u01 = ((const f32x4*)p0)[1];
                f32x4 u10 = ((const f32x4*)p1)[0], u11 = ((const f32x4*)p1)[1];
                a0[0] = f2bf(u00[0]); a0[1] = f2bf(u00[1]); a0[2] = f2bf(u00[2]); a0[3] = f2bf(u00[3]);
                a0[4] = f2bf(u01[0]); a0[5] = f2bf(u01[1]); a0[6] = f2bf(u01[2]); a0[7] = f2bf(u01[3]);
                a1[0] = f2bf(u10[0]); a1[1] = f2bf(u10[1]); a1[2] = f2bf(u10[2]); a1[3] = f2bf(u10[3]);
                a1[4] = f2bf(u11[0]); a1[5] = f2bf(u11[1]); a1[6] = f2bf(u11[2]); a1[7] = f2bf(u11[3]);
            } else {
                // h chunk: bf16 recurrent input
                const short* hp = hcur + (size_t)mA0 * HID + (ci * 32 - IN_DIM) + lq * 8;
                a0 = *(const bf16x8*)hp;
                a1 = *(const bf16x8*)(hp + (size_t)16 * HID);
            }
            #pragma unroll
            for (int g = 0; g < 4; ++g) {
                acc[0][g] = __builtin_amdgcn_mfma_f32_16x16x32_bf16(a0, Bf[i][g], acc[0][g], 0, 0, 0);
                acc[1][g] = __builtin_amdgcn_mfma_f32_16x16x32_bf16(a1, Bf[i][g], acc[1][g], 0, 0, 0);
            }
        }

        // ---- write K-partials to LDS (f32x4, b128) ----
        #pragma unroll
        for (int ms = 0; ms < 2; ++ms)
            #pragma unroll
            for (int g = 0; g < 4; ++g)
                *(f32x4*)&q[(((kw * 4 + g) * 4 + mh * 2 + ms) * 64 + l) * 4] = acc[ms][g];
        __syncthreads();

        // ---- gather 4 K-partials, cell update for 2 cells ----
        float sA[4] = {0.f, 0.f, 0.f, 0.f};
        float sB[4] = {0.f, 0.f, 0.f, 0.f};
        #pragma unroll
        for (int kk = 0; kk < 4; ++kk)
            #pragma unroll
            for (int g = 0; g < 4; ++g) {
                f32x2 v = *(const f32x2*)&q[((kk * 4 + g) * 4 + mgrp) * 256 + l * 4 + rp];
                sA[g] += v[0];
                sB[g] += v[1];
            }
        {
            float ig = sigmoidf_fast(sA[0] + bia[0]);
            float fg = sigmoidf_fast(sA[1] + bia[1]);
            float gg = tanhf_fast(sA[2] + bia[2]);
            float og = sigmoidf_fast(sA[3] + bia[3]);
            c0 = fg * c0 + ig * gg;
            hnext[(size_t)(m0 + mcell) * HID + jc] = f2bf(og * tanhf_fast(c0));
        }
        {
            float ig = sigmoidf_fast(sB[0] + bia[0]);
            float fg = sigmoidf_fast(sB[1] + bia[1]);
            float gg = tanhf_fast(sB[2] + bia[2]);
            float og = sigmoidf_fast(sB[3] + bia[3]);
            c1 = fg * c1 + ig * gg;
            hnext[(size_t)(m0 + mcell + 1) * HID + jc] = f2bf(og * tanhf_fast(c1));
        }

        grid.sync();   // also orders LDS reads (above) before next iter's LDS writes
    }

    // ---- epilogue: out[b] = sum_j c[b,j]*fcw[j] + fcb ----
    const float fw = fcw[jc];
    float vA = c0 * fw, vB = c1 * fw;
    vA += __shfl_xor(vA, 1); vA += __shfl_xor(vA, 2);
    vA += __shfl_xor(vA, 4); vA += __shfl_xor(vA, 8);
    vB += __shfl_xor(vB, 1); vB += __shfl_xor(vB, 2);
    vB += __shfl_xor(vB, 4); vB += __shfl_xor(vB, 8);
    if (r16 == 0) {
        float add = (j0 == 0) ? fcb[0] : 0.f;
        atomicAdd(&out[m0 + mcell],     vA + add);
        atomicAdd(&out[m0 + mcell + 1], vB + add);
    }
}

extern "C" void kernel_launch(void* const* d_in, const int* in_sizes, int n_in,
                              void* d_out, int out_size, void* d_ws, size_t ws_size,
                              hipStream_t stream)
{
    (void)in_sizes; (void)n_in; (void)out_size; (void)ws_size;
    const float* x   = (const float*)d_in[0];
    const float* wih = (const float*)d_in[1];
    const float* whh = (const float*)d_in[2];
    const float* bih = (const float*)d_in[3];
    const float* bhh = (const float*)d_in[4];
    const float* fcw = (const float*)d_in[5];
    const float* fcb = (const float*)d_in[6];
    float* out = (float*)d_out;

    char* ws = (char*)d_ws;
    short* wcat = (short*)ws;                                   // 10,485,760 B
    float* bias = (float*)(ws + 10485760);                      // 16,384 B
    short* h0   = (short*)(ws + 10485760 + 16384);              // 524,288 B
    short* h1   = h0 + BATCH * HID;                             // 524,288 B

    prep_wcat<<<(4096 * KTOT + 255) / 256, 256, 0, stream>>>(wih, whh, wcat);
    prep_misc<<<(BATCH * HID + 255) / 256, 256, 0, stream>>>(bih, bhh, bias, h0, h1, out);

    static bool attr_set = false;
    hipFuncSetAttribute((const void*)lstm_main,
                        hipFuncAttributeMaxDynamicSharedMemorySize, 65536);
    (void)attr_set;

    void* args[] = { (void*)&x, (void*)&wcat, (void*)&bias, (void*)&fcw, (void*)&fcb,
                     (void*)&h0, (void*)&h1, (void*)&out };
    hipLaunchCooperativeKernel((void*)lstm_main, dim3(256), dim3(512), args, 65536, stream);
}

// Round 3
// 12392.557 us; speedup vs baseline: 2.2087x; 1.5642x over previous
//
#include <hip/hip_runtime.h>

// Problem dims
#define BATCH   256
#define T_STEPS 512
#define IN_DIM  256
#define HID     1024
#define KTOT    1280   // IN_DIM + HID
#define CKW     10     // K chunks of 32 per wave (K-quarter)

typedef __attribute__((ext_vector_type(4))) float f32x4;
typedef __attribute__((ext_vector_type(2))) float f32x2;
typedef __attribute__((ext_vector_type(8))) short bf16x8;

__device__ inline short f2bf(float f) {
    union { float f; unsigned u; } v; v.f = f;
    unsigned u = v.u;
    unsigned r = (u + 0x7fffu + ((u >> 16) & 1u)) >> 16;  // RNE
    return (short)r;
}

__device__ inline float sigmoidf_fast(float x) {
    return __builtin_amdgcn_rcpf(1.0f + __expf(-x));
}
__device__ inline float tanhf_fast(float x) {
    return 1.0f - 2.0f * __builtin_amdgcn_rcpf(1.0f + __expf(2.0f * x));
}

// write-through bf16 store: bypasses L2, lands at the device coherence point
__device__ inline void store_bf16_wt(short* p, unsigned v) {
    asm volatile("global_store_short %0, %1, off sc0 sc1" :: "v"(p), "v"(v) : "memory");
}

// Build w_cat bf16 [4096][1280] = [w_ih | w_hh] rows (N-major, K contiguous)
__global__ void prep_wcat(const float* __restrict__ wih, const float* __restrict__ whh,
                          short* __restrict__ wcat) {
    int i = blockIdx.x * 256 + threadIdx.x;
    if (i >= 4096 * KTOT) return;
    int g = i / KTOT;
    int k = i - g * KTOT;
    float v = (k < IN_DIM) ? wih[g * IN_DIM + k] : whh[(size_t)g * HID + (k - IN_DIM)];
    wcat[i] = f2bf(v);
}

// bias_comb = b_ih + b_hh; zero h buffers, barrier flags, output
__global__ void prep_misc(const float* __restrict__ bih, const float* __restrict__ bhh,
                          float* __restrict__ bias, short* __restrict__ h0,
                          short* __restrict__ h1, float* __restrict__ out,
                          int* __restrict__ flags) {
    int i = blockIdx.x * 256 + threadIdx.x;
    if (i < 4096) bias[i] = bih[i] + bhh[i];
    if (i < BATCH * HID) { h0[i] = 0; h1[i] = 0; }
    if (i < BATCH) out[i] = 0.0f;
    if (i < 256) flags[i] = 0;
}

// Persistent cooperative LSTM kernel, register-resident weights, custom barrier.
// Grid: 256 blocks = 4 m-groups (64 batch rows) x 64 j-tiles (16 cols, 4 gates).
// Block: 512 threads = 8 waves = (m-half mh) x (K-quarter kw). Weights live in
// registers all 512 steps. Barrier is per-m-group (64 blocks): h exchanged
// write-through at LLC, flag store + 64-lane poll, buffer_inv for acquire.
__global__ __launch_bounds__(512, 2) void lstm_main(
    const float* __restrict__ x, const short* __restrict__ wcat,
    const float* __restrict__ bias, const float* __restrict__ fcw,
    const float* __restrict__ fcb, short* __restrict__ h0,
    short* __restrict__ h1, float* __restrict__ out, int* __restrict__ flags)
{
    extern __shared__ float q[];   // [kw][g][mgrp][lane][4] floats = 64 KB

    const int tid = threadIdx.x;
    const int l   = tid & 63;
    const int u   = tid >> 6;        // wave 0..7
    const int mh  = u >> 2;          // m-half 0..1
    const int kw  = u & 3;           // K-quarter 0..3
    const int lq  = l >> 4;          // lane quad 0..3
    const int r16 = l & 15;
    const int grp = blockIdx.x >> 6;         // m-group 0..3
    const int jblk = blockIdx.x & 63;        // j-block within group
    const int m0  = grp * 64;
    const int j0  = jblk * 16;
    const int jc  = j0 + r16;
    int* const gflags = flags + grp * 64;

    // ---- persistent B fragments: 10 chunks x 4 gates, register-resident ----
    bf16x8 Bf[CKW][4];
    #pragma unroll
    for (int i = 0; i < CKW; ++i) {
        const int k = (kw * CKW + i) * 32 + lq * 8;
        #pragma unroll
        for (int g = 0; g < 4; ++g)
            Bf[i][g] = *(const bf16x8*)(wcat + (size_t)(g * HID + jc) * KTOT + k);
    }

    // ---- update-phase cell ownership: 2 cells per thread ----
    const int mgrp  = u >> 1;            // 0..3
    const int rp    = (u & 1) * 2;       // r-pair base
    const int mcell = mgrp * 16 + lq * 4 + rp;
    float bia[4];
    #pragma unroll
    for (int g = 0; g < 4; ++g) bia[g] = bias[g * HID + jc];
    float c0 = 0.f, c1 = 0.f;

    // ---- A-operand addressing ----
    const int mA0 = m0 + mh * 32 + r16;
    const float* xb0 = x + (size_t)mA0 * (T_STEPS * IN_DIM) + lq * 8;
    const float* xb1 = x + (size_t)(mA0 + 16) * (T_STEPS * IN_DIM) + lq * 8;

    for (int t = 0; t < T_STEPS; ++t) {
        const short* hcur  = (t & 1) ? h1 : h0;
        short*       hnext = (t & 1) ? h0 : h1;

        f32x4 acc[2][4] = {};   // [m-subtile][gate]

        #pragma unroll
        for (int i = 0; i < CKW; ++i) {
            const int ci = kw * CKW + i;
            bf16x8 a0, a1;
            if (ci < 8) {
                const float* p0 = xb0 + (size_t)t * IN_DIM + ci * 32;
                const float* p1 = xb1 + (size_t)t * IN_DIM + ci * 32;
                f32x4 u00 = ((const f32x4*)p0)[0], u01 = ((const f32x4*)p0)[1];
                f32x4 u10 = ((const f32x4*)p1)[0], u11 = ((const f32x4*)p1)[1];
                a0[0] = f2bf(u00[0]); a0[1] = f2bf(u00[1]); a0[2] = f2bf(u00[2]); a0[3] = f2bf(u00[3]);
                a0[4] = f2bf(u01[0]); a0[5] = f2bf(u01[1]); a0[6] = f2bf(u01[2]); a0[7] = f2bf(u01[3]);
                a1[0] = f2bf(u10[0]); a1[1] = f2bf(u10[1]); a1[2] = f2bf(u10[2]); a1[3] = f2bf(u10[3]);
                a1[4] = f2bf(u11[0]); a1[5] = f2bf(u11[1]); a1[6] = f2bf(u11[2]); a1[7] = f2bf(u11[3]);
            } else {
                const short* hp = hcur + (size_t)mA0 * HID + (ci * 32 - IN_DIM) + lq * 8;
                a0 = *(const bf16x8*)hp;
                a1 = *(const bf16x8*)(hp + (size_t)16 * HID);
            }
            #pragma unroll
            for (int g = 0; g < 4; ++g) {
                acc[0][g] = __builtin_amdgcn_mfma_f32_16x16x32_bf16(a0, Bf[i][g], acc[0][g], 0, 0, 0);
                acc[1][g] = __builtin_amdgcn_mfma_f32_16x16x32_bf16(a1, Bf[i][g], acc[1][g], 0, 0, 0);
            }
        }

        // ---- write K-partials to LDS ----
        #pragma unroll
        for (int ms = 0; ms < 2; ++ms)
            #pragma unroll
            for (int g = 0; g < 4; ++g)
                *(f32x4*)&q[(((kw * 4 + g) * 4 + mh * 2 + ms) * 64 + l) * 4] = acc[ms][g];
        __syncthreads();

        // ---- gather 4 K-partials, cell update for 2 cells ----
        float sA[4] = {0.f, 0.f, 0.f, 0.f};
        float sB[4] = {0.f, 0.f, 0.f, 0.f};
        #pragma unroll
        for (int kk = 0; kk < 4; ++kk)
            #pragma unroll
            for (int g = 0; g < 4; ++g) {
                f32x2 v = *(const f32x2*)&q[((kk * 4 + g) * 4 + mgrp) * 256 + l * 4 + rp];
                sA[g] += v[0];
                sB[g] += v[1];
            }
        {
            float ig = sigmoidf_fast(sA[0] + bia[0]);
            float fg = sigmoidf_fast(sA[1] + bia[1]);
            float gg = tanhf_fast(sA[2] + bia[2]);
            float og = sigmoidf_fast(sA[3] + bia[3]);
            c0 = fg * c0 + ig * gg;
            store_bf16_wt(hnext + (size_t)(m0 + mcell) * HID + jc,
                          (unsigned)(unsigned short)f2bf(og * tanhf_fast(c0)));
        }
        {
            float ig = sigmoidf_fast(sB[0] + bia[0]);
            float fg = sigmoidf_fast(sB[1] + bia[1]);
            float gg = tanhf_fast(sB[2] + bia[2]);
            float og = sigmoidf_fast(sB[3] + bia[3]);
            c1 = fg * c1 + ig * gg;
            store_bf16_wt(hnext + (size_t)(m0 + mcell + 1) * HID + jc,
                          (unsigned)(unsigned short)f2bf(og * tanhf_fast(c1)));
        }

        // ---- per-m-group barrier (64 blocks) ----
        // drain this wave's write-through stores, then block-wide rendezvous
        asm volatile("s_waitcnt vmcnt(0)" ::: "memory");
        __syncthreads();                    // all 512 threads' h stores are at LLC
        if (tid == 0)
            __hip_atomic_store(&gflags[jblk], t + 1, __ATOMIC_RELAXED,
                               __HIP_MEMORY_SCOPE_AGENT);
        if (tid < 64) {
            const int target = t + 1;
            while (true) {
                int v = __hip_atomic_load(&gflags[tid], __ATOMIC_RELAXED,
                                          __HIP_MEMORY_SCOPE_AGENT);
                if (__ballot(v < target) == 0ull) break;
                __builtin_amdgcn_s_sleep(1);
            }
        }
        __syncthreads();
        // acquire: invalidate L1 + local-L2 stale lines so next step's plain
        // h loads observe the LLC data (weights are in registers; x is
        // consumed same-step, so this costs nothing for them)
        asm volatile("buffer_inv sc1" ::: "memory");
    }

    // ---- epilogue: out[b] = sum_j c[b,j]*fcw[j] + fcb ----
    const float fw = fcw[jc];
    float vA = c0 * fw, vB = c1 * fw;
    vA += __shfl_xor(vA, 1); vA += __shfl_xor(vA, 2);
    vA += __shfl_xor(vA, 4); vA += __shfl_xor(vA, 8);
    vB += __shfl_xor(vB, 1); vB += __shfl_xor(vB, 2);
    vB += __shfl_xor(vB, 4); vB += __shfl_xor(vB, 8);
    if (r16 == 0) {
        float add = (j0 == 0) ? fcb[0] : 0.f;
        atomicAdd(&out[m0 + mcell],     vA + add);
        atomicAdd(&out[m0 + mcell + 1], vB + add);
    }
}

extern "C" void kernel_launch(void* const* d_in, const int* in_sizes, int n_in,
                              void* d_out, int out_size, void* d_ws, size_t ws_size,
                              hipStream_t stream)
{
    (void)in_sizes; (void)n_in; (void)out_size; (void)ws_size;
    const float* x   = (const float*)d_in[0];
    const float* wih = (const float*)d_in[1];
    const float* whh = (const float*)d_in[2];
    const float* bih = (const float*)d_in[3];
    const float* bhh = (const float*)d_in[4];
    const float* fcw = (const float*)d_in[5];
    const float* fcb = (const float*)d_in[6];
    float* out = (float*)d_out;

    char* ws = (char*)d_ws;
    short* wcat  = (short*)ws;                                  // 10,485,760 B
    float* bias  = (float*)(ws + 10485760);                     // 16,384 B
    short* h0    = (short*)(ws + 10485760 + 16384);             // 524,288 B
    short* h1    = h0 + BATCH * HID;                            // 524,288 B
    int*   flags = (int*)(ws + 10485760 + 16384 + 2 * 524288);  // 1,024 B

    prep_wcat<<<(4096 * KTOT + 255) / 256, 256, 0, stream>>>(wih, whh, wcat);
    prep_misc<<<(BATCH * HID + 255) / 256, 256, 0, stream>>>(bih, bhh, bias, h0, h1, out, flags);

    hipFuncSetAttribute((const void*)lstm_main,
                        hipFuncAttributeMaxDynamicSharedMemorySize, 65536);

    void* args[] = { (void*)&x, (void*)&wcat, (void*)&bias, (void*)&fcw, (void*)&fcb,
                     (void*)&h0, (void*)&h1, (void*)&out, (void*)&flags };
    hipLaunchCooperativeKernel((void*)lstm_main, dim3(256), dim3(512), args, 65536, stream);
}

// Round 5
// 11636.032 us; speedup vs baseline: 2.3523x; 1.0650x over previous
//
#include <hip/hip_runtime.h>

// Problem dims
#define BATCH   256
#define T_STEPS 512
#define IN_DIM  256
#define HID     1024
#define KTOT    1280   // IN_DIM + HID
#define CKW     10     // K chunks of 32 per wave (K-quarter)

// Dynamic LDS: 64 KB partials (q) + 2 KB h staging (hs) = 67,584 B.
// 2 blocks/CU x 67,584 = 135,168 <= 160 KB. (Round 4 failed by allocating
// only 66,560 -> hs rows 32..63 landed in the neighbor block's LDS.)
#define DYN_LDS 67584

typedef __attribute__((ext_vector_type(4))) float f32x4;
typedef __attribute__((ext_vector_type(8))) short bf16x8;
typedef __attribute__((ext_vector_type(4))) short s16x4;

__device__ inline short f2bf(float f) {
    union { float f; unsigned u; } v; v.f = f;
    unsigned u = v.u;
    unsigned r = (u + 0x7fffu + ((u >> 16) & 1u)) >> 16;  // RNE
    return (short)r;
}

__device__ inline float sigmoidf_fast(float x) {
    return __builtin_amdgcn_rcpf(1.0f + __expf(-x));
}
__device__ inline float tanhf_fast(float x) {
    return 1.0f - 2.0f * __builtin_amdgcn_rcpf(1.0f + __expf(2.0f * x));
}

// full-line write-through store: 16 B, lands at the device coherence point
__device__ inline void store_wt16(void* p, f32x4 d) {
    asm volatile("global_store_dwordx4 %0, %1, off sc0 sc1" :: "v"(p), "v"(d) : "memory");
}

// Build w_cat bf16 [4096][1280] = [w_ih | w_hh] rows (N-major, K contiguous)
__global__ void prep_wcat(const float* __restrict__ wih, const float* __restrict__ whh,
                          short* __restrict__ wcat) {
    int i = blockIdx.x * 256 + threadIdx.x;
    if (i >= 4096 * KTOT) return;
    int g = i / KTOT;
    int k = i - g * KTOT;
    float v = (k < IN_DIM) ? wih[g * IN_DIM + k] : whh[(size_t)g * HID + (k - IN_DIM)];
    wcat[i] = f2bf(v);
}

// x [b][t][k] fp32 -> xt [t][b][k] bf16 (time-major: per-step slice contiguous)
__global__ void prep_xt(const float* __restrict__ x, short* __restrict__ xt) {
    int i = blockIdx.x * 256 + threadIdx.x;
    int o = i * 4;                    // output linear index, 4 elems/thread
    if (o >= BATCH * T_STEPS * IN_DIM) return;
    int k  = o & (IN_DIM - 1);
    int bt = o >> 8;
    int b  = bt & (BATCH - 1);
    int t  = bt >> 8;
    f32x4 v = *(const f32x4*)(x + ((size_t)(b * T_STEPS + t) << 8) + k);
    s16x4 s;
    s[0] = f2bf(v[0]); s[1] = f2bf(v[1]); s[2] = f2bf(v[2]); s[3] = f2bf(v[3]);
    *(s16x4*)(xt + o) = s;
}

// bias_comb = b_ih + b_hh; zero h buffers, barrier flags, output
__global__ void prep_misc(const float* __restrict__ bih, const float* __restrict__ bhh,
                          float* __restrict__ bias, short* __restrict__ h0,
                          short* __restrict__ h1, float* __restrict__ out,
                          int* __restrict__ flags) {
    int i = blockIdx.x * 256 + threadIdx.x;
    if (i < 4096) bias[i] = bih[i] + bhh[i];
    if (i < BATCH * HID) { h0[i] = 0; h1[i] = 0; }
    if (i < BATCH) out[i] = 0.0f;
    if (i < 256) flags[i] = 0;
}

// Persistent cooperative LSTM kernel, register-resident weights, custom
// per-m-group barrier, TILED h layout hT[jt][b][jr] so each block's h output
// is a contiguous 2 KB slab written with full-line write-through dwordx4.
// Grid: 256 blocks = 4 m-groups (64 rows) x 64 j-tiles (16 h-cols, 4 gates).
// Block: 512 threads = 8 waves = (m-half mh) x (K-quarter kw).
template<bool XBF>
__global__ __launch_bounds__(512, 2) void lstm_main(
    const float* __restrict__ x, const short* __restrict__ xt,
    const short* __restrict__ wcat, const float* __restrict__ bias,
    const float* __restrict__ fcw, const float* __restrict__ fcb,
    short* __restrict__ h0, short* __restrict__ h1,
    float* __restrict__ out, int* __restrict__ flags)
{
    extern __shared__ float q[];          // 64 KB partials + 2 KB h staging
    short* hs = (short*)(q + 16384);      // [64 rows][16 cols] bf16 tile

    const int tid = threadIdx.x;
    const int l   = tid & 63;
    const int u   = tid >> 6;        // wave 0..7
    const int mh  = u >> 2;          // m-half 0..1
    const int kw  = u & 3;           // K-quarter 0..3
    const int lq  = l >> 4;          // lane quad 0..3
    const int r16 = l & 15;
    const int grp = blockIdx.x >> 6;         // m-group 0..3
    const int jblk = blockIdx.x & 63;        // j-tile within group
    const int m0  = grp * 64;
    const int j0  = jblk * 16;
    const int jc  = j0 + r16;
    int* const gflags = flags + grp * 64;

    // ---- persistent B fragments: 10 chunks x 4 gates, register-resident ----
    bf16x8 Bf[CKW][4];
    #pragma unroll
    for (int i = 0; i < CKW; ++i) {
        const int k = (kw * CKW + i) * 32 + lq * 8;
        #pragma unroll
        for (int g = 0; g < 4; ++g)
            Bf[i][g] = *(const bf16x8*)(wcat + (size_t)(g * HID + jc) * KTOT + k);
    }

    // ---- update-phase cell ownership: 2 cells per thread ----
    const int mgrp  = u >> 1;            // 0..3
    const int rp    = (u & 1) * 2;       // r-pair base (0 or 2)
    const int mcell = mgrp * 16 + lq * 4 + rp;
    float bia[4];
    #pragma unroll
    for (int g = 0; g < 4; ++g) bia[g] = bias[g * HID + jc];
    float c0 = 0.f, c1 = 0.f;

    // ---- A-operand addressing ----
    const int mA0 = m0 + mh * 32 + r16;   // rows mA0 and mA0+16
    const float* xb0 = x + (size_t)mA0 * (T_STEPS * IN_DIM) + lq * 8;
    const float* xb1 = x + (size_t)(mA0 + 16) * (T_STEPS * IN_DIM) + lq * 8;

    for (int t = 0; t < T_STEPS; ++t) {
        const short* hcurT  = (t & 1) ? h1 : h0;
        short*       hnextT = (t & 1) ? h0 : h1;

        f32x4 acc[2][4] = {};   // [m-subtile][gate]

        #pragma unroll
        for (int i = 0; i < CKW; ++i) {
            const int ci = kw * CKW + i;
            bf16x8 a0, a1;
            if (ci < 8) {
                if (XBF) {
                    const short* p = xt + ((size_t)(t * BATCH + mA0) << 8) + ci * 32 + lq * 8;
                    a0 = *(const bf16x8*)p;
                    a1 = *(const bf16x8*)(p + (16 << 8));
                } else {
                    const float* p0 = xb0 + (size_t)t * IN_DIM + ci * 32;
                    const float* p1 = xb1 + (size_t)t * IN_DIM + ci * 32;
                    f32x4 u00 = ((const f32x4*)p0)[0], u01 = ((const f32x4*)p0)[1];
                    f32x4 u10 = ((const f32x4*)p1)[0], u11 = ((const f32x4*)p1)[1];
                    a0[0] = f2bf(u00[0]); a0[1] = f2bf(u00[1]); a0[2] = f2bf(u00[2]); a0[3] = f2bf(u00[3]);
                    a0[4] = f2bf(u01[0]); a0[5] = f2bf(u01[1]); a0[6] = f2bf(u01[2]); a0[7] = f2bf(u01[3]);
                    a1[0] = f2bf(u10[0]); a1[1] = f2bf(u10[1]); a1[2] = f2bf(u10[2]); a1[3] = f2bf(u10[3]);
                    a1[4] = f2bf(u11[0]); a1[5] = f2bf(u11[1]); a1[6] = f2bf(u11[2]); a1[7] = f2bf(u11[3]);
                }
            } else {
                // h chunk from tiled layout hT[jt][b][jr]
                const int k0 = ci * 32 - IN_DIM + lq * 8;
                const int jt = k0 >> 4;
                const int jr0 = k0 & 15;          // 0 or 8
                const short* hp = hcurT + ((size_t)(jt * BATCH + mA0) << 4) + jr0;
                a0 = *(const bf16x8*)hp;
                a1 = *(const bf16x8*)(hp + (16 << 4));
            }
            #pragma unroll
            for (int g = 0; g < 4; ++g) {
                acc[0][g] = __builtin_amdgcn_mfma_f32_16x16x32_bf16(a0, Bf[i][g], acc[0][g], 0, 0, 0);
                acc[1][g] = __builtin_amdgcn_mfma_f32_16x16x32_bf16(a1, Bf[i][g], acc[1][g], 0, 0, 0);
            }
        }

        // ---- write K-partials to LDS (b128) ----
        #pragma unroll
        for (int ms = 0; ms < 2; ++ms)
            #pragma unroll
            for (int g = 0; g < 4; ++g)
                *(f32x4*)&q[(((kw * 4 + g) * 4 + mh * 2 + ms) * 64 + l) * 4] = acc[ms][g];
        __syncthreads();

        // ---- gather 4 K-partials via b128 reads (wave-uniform parity) ----
        float sA[4] = {0.f, 0.f, 0.f, 0.f};
        float sB[4] = {0.f, 0.f, 0.f, 0.f};
        if ((u & 1) == 0) {
            #pragma unroll
            for (int kk = 0; kk < 4; ++kk)
                #pragma unroll
                for (int g = 0; g < 4; ++g) {
                    f32x4 v = *(const f32x4*)&q[(((kk * 4 + g) * 4 + mgrp) * 64 + l) * 4];
                    sA[g] += v[0]; sB[g] += v[1];
                }
        } else {
            #pragma unroll
            for (int kk = 0; kk < 4; ++kk)
                #pragma unroll
                for (int g = 0; g < 4; ++g) {
                    f32x4 v = *(const f32x4*)&q[(((kk * 4 + g) * 4 + mgrp) * 64 + l) * 4];
                    sA[g] += v[2]; sB[g] += v[3];
                }
        }

        // ---- cell update for 2 cells, h -> LDS staging tile ----
        {
            float ig = sigmoidf_fast(sA[0] + bia[0]);
            float fg = sigmoidf_fast(sA[1] + bia[1]);
            float gg = tanhf_fast(sA[2] + bia[2]);
            float og = sigmoidf_fast(sA[3] + bia[3]);
            c0 = fg * c0 + ig * gg;
            hs[mcell * 16 + r16] = f2bf(og * tanhf_fast(c0));
        }
        {
            float ig = sigmoidf_fast(sB[0] + bia[0]);
            float fg = sigmoidf_fast(sB[1] + bia[1]);
            float gg = tanhf_fast(sB[2] + bia[2]);
            float og = sigmoidf_fast(sB[3] + bia[3]);
            c1 = fg * c1 + ig * gg;
            hs[(mcell + 1) * 16 + r16] = f2bf(og * tanhf_fast(c1));
        }
        __syncthreads();

        // ---- coalesced full-line write-through of the 2 KB h slab ----
        if (tid < 128) {
            f32x4 d = *(const f32x4*)((const char*)hs + tid * 16);
            short* dst = hnextT + ((size_t)(jblk * BATCH + m0) << 4) + tid * 8;
            store_wt16(dst, d);
        }
        asm volatile("s_waitcnt vmcnt(0)" ::: "memory");
        __syncthreads();                    // all h stores are at the LLC

        // ---- per-m-group barrier (64 blocks) ----
        if (tid == 0)
            __hip_atomic_store(&gflags[jblk], t + 1, __ATOMIC_RELAXED,
                               __HIP_MEMORY_SCOPE_AGENT);
        if (tid < 64) {
            const int target = t + 1;
            while (true) {
                int v = __hip_atomic_load(&gflags[tid], __ATOMIC_RELAXED,
                                          __HIP_MEMORY_SCOPE_AGENT);
                if (__ballot(v < target) == 0ull) break;
                __builtin_amdgcn_s_sleep(1);
            }
        }
        __syncthreads();
        // acquire: drop stale L1/L2 lines so next step's h loads see LLC data
        asm volatile("buffer_inv sc1" ::: "memory");
    }

    // ---- epilogue: out[b] = sum_j c[b,j]*fcw[j] + fcb ----
    const float fw = fcw[jc];
    float vA = c0 * fw, vB = c1 * fw;
    vA += __shfl_xor(vA, 1); vA += __shfl_xor(vA, 2);
    vA += __shfl_xor(vA, 4); vA += __shfl_xor(vA, 8);
    vB += __shfl_xor(vB, 1); vB += __shfl_xor(vB, 2);
    vB += __shfl_xor(vB, 4); vB += __shfl_xor(vB, 8);
    if (r16 == 0) {
        float add = (j0 == 0) ? fcb[0] : 0.f;
        atomicAdd(&out[m0 + mcell],     vA + add);
        atomicAdd(&out[m0 + mcell + 1], vB + add);
    }
}

extern "C" void kernel_launch(void* const* d_in, const int* in_sizes, int n_in,
                              void* d_out, int out_size, void* d_ws, size_t ws_size,
                              hipStream_t stream)
{
    (void)in_sizes; (void)n_in; (void)out_size;
    const float* x   = (const float*)d_in[0];
    const float* wih = (const float*)d_in[1];
    const float* whh = (const float*)d_in[2];
    const float* bih = (const float*)d_in[3];
    const float* bhh = (const float*)d_in[4];
    const float* fcw = (const float*)d_in[5];
    const float* fcb = (const float*)d_in[6];
    float* out = (float*)d_out;

    char* ws = (char*)d_ws;
    short* wcat  = (short*)ws;                                  // 10,485,760 B
    float* bias  = (float*)(ws + 10485760);                     // 16,384 B
    short* h0    = (short*)(ws + 10485760 + 16384);             // 524,288 B (tiled)
    short* h1    = h0 + BATCH * HID;                            // 524,288 B (tiled)
    int*   flags = (int*)(ws + 10485760 + 16384 + 2 * 524288);  // 1,024 B
    short* xt    = (short*)(ws + 11551744);                     // 67,108,864 B
    const size_t WS_NEEDED = 11551744ull + 67108864ull;         // 78,660,608 B
    const bool use_xbf = (ws_size >= WS_NEEDED);

    prep_wcat<<<(4096 * KTOT + 255) / 256, 256, 0, stream>>>(wih, whh, wcat);
    prep_misc<<<(BATCH * HID + 255) / 256, 256, 0, stream>>>(bih, bhh, bias, h0, h1, out, flags);
    if (use_xbf)
        prep_xt<<<(BATCH * T_STEPS * IN_DIM / 4 + 255) / 256, 256, 0, stream>>>(x, xt);

    void* fn = use_xbf ? (void*)lstm_main<true> : (void*)lstm_main<false>;
    hipFuncSetAttribute(fn, hipFuncAttributeMaxDynamicSharedMemorySize, DYN_LDS);

    void* args[] = { (void*)&x, (void*)&xt, (void*)&wcat, (void*)&bias,
                     (void*)&fcw, (void*)&fcb, (void*)&h0, (void*)&h1,
                     (void*)&out, (void*)&flags };
    hipLaunchCooperativeKernel(fn, dim3(256), dim3(512), args, DYN_LDS, stream);
}